// Round 6
// baseline (279.449 us; speedup 1.0000x reference)
//
#include <hip/hip_runtime.h>

// Problem constants (static shapes from reference)
#define B 64
#define C 2048
#define H 24
#define W 8
#define HW (H * W)            // 192 spatial positions per (b,c)
#define HW4 (HW / 4)          // 48 float4 per channel row
#define CHUNKS 16             // channel chunks per batch
#define CPC (C / CHUNKS)      // 128 channels per chunk
#define RH 8                  // round(0.33 * 24) = 8 rows zeroed
#define CHW4 ((C * HW) / 4)   // float4s per batch = 98304
#define GRID (B * CHUNKS)     // 1024 blocks: one (b,chunk) each
#define TPB 192               // 3 waves

typedef float f32x4 __attribute__((ext_vector_type(4)));

// ---------------------------------------------------------------------------
// Init: zero the per-batch arrival counters (ws is poisoned every iteration;
// this launch is in the captured graph so it replays each time).
// ---------------------------------------------------------------------------
__global__ __launch_bounds__(64) void k_init(unsigned int* __restrict__ counters) {
    if (threadIdx.x < B) counters[threadIdx.x] = 0u;
}

// ---------------------------------------------------------------------------
// Single-pass kernel. Per (b,chunk) block:
//   Phase 1: sumsq over this chunk's 128 channels -> partial4 (verbatim
//            verified k_ss math).
//   Sync:    per-BATCH semaphore — release atomicAdd on counters[b], then a
//            BOUNDED acquire-spin until all 16 chunk-blocks arrive. Only 16
//            blocks rendezvous (not 1024 — the cg::grid.sync mistake).
//            Co-residency: 1024 blocks x 3 waves, ~40 VGPR, 3.2 KB LDS ->
//            ~10 blocks/CU capacity vs 4 needed; all blocks resident from
//            dispatch, so the spin terminates. The iteration bound (~85 ms)
//            converts any sync failure into a wrong answer (absmax>0,
//            diagnosable) instead of a container hang.
//   Phase 2: rank rows from the batch's 12 KB of partials (L2-hot) ->
//            smask in LDS (verbatim verified tie-break math).
//   Phase 3: out = x * m over the SAME addresses phase 1 read (L3-warm,
//            proven by Round-3 FETCH=99MB), nontemporal stores.
// HBM total ~ read x once + write out once = 201 MB -> ~32 us floor.
// ---------------------------------------------------------------------------
__global__ __launch_bounds__(TPB) void k_one(const f32x4* __restrict__ x4,
                                             f32x4* __restrict__ partial4,
                                             unsigned int* __restrict__ counters,
                                             f32x4* __restrict__ out4) {
    const int blk = blockIdx.x;
    const int b = blk / CHUNKS;
    const int chunk = blk % CHUNKS;
    const int t = threadIdx.x;
    const int q = t % HW4;   // float4 spatial position (fixed per thread)
    const int g = t / HW4;   // channel subgroup (0..3)

    const size_t xoff = (size_t)(b * C + chunk * CPC + g) * HW4 + q;
    const f32x4* p = x4 + xoff;

    // ---- Phase 1: sum of squares (verbatim verified k_ss) ----
    f32x4 acc = {0.f, 0.f, 0.f, 0.f};
    #pragma unroll
    for (int j = 0; j < CPC / 4; ++j) {          // 32 iters, 16 B/lane coalesced
        const f32x4 v = p[(size_t)j * 4 * HW4];
        acc += v * v;
    }
    __shared__ f32x4 sm[4][HW4];  // 3 KB
    __shared__ float smask[H];
    sm[g][q] = acc;
    __syncthreads();
    if (t < HW4)
        partial4[(size_t)blk * HW4 + t] =
            (sm[0][t] + sm[1][t]) + (sm[2][t] + sm[3][t]);
    __syncthreads();  // partial stores issued before the release fence

    // ---- Per-batch semaphore (bounded spin) ----
    if (t == 0) {
        __threadfence();              // agent-scope release of partial stores
        atomicAdd(&counters[b], 1u);  // device-scope RMW (guide m20)
        unsigned int spins = 0;
        while (__hip_atomic_load(&counters[b], __ATOMIC_ACQUIRE,
                                 __HIP_MEMORY_SCOPE_AGENT) < CHUNKS) {
            __builtin_amdgcn_s_sleep(8);
            if (++spins > 400000u) break;  // ~85 ms: impossible unless sync is
                                           // broken -> wrong answer, not hang
        }
    }
    __syncthreads();

    // ---- Phase 2: rank rows (verbatim verified k_mask math; wave 0) ----
    if (t < 64) {
        f32x4 s = {0.f, 0.f, 0.f, 0.f};
        if (t < HW4) {
            #pragma unroll
            for (int ch = 0; ch < CHUNKS; ++ch)  // fixed order: deterministic
                s += partial4[(size_t)(b * CHUNKS + ch) * HW4 + t];
        }
        float m = fmaxf(fmaxf(s.x, s.y), fmaxf(s.z, s.w));
        m = fmaxf(m, __shfl_xor(m, 1));  // row h max now at lane 2h
        const float my = __shfl(m, 2 * (t < H ? t : 0));
        int cnt = 0;
        #pragma unroll
        for (int h = 0; h < H; ++h) {
            const float o = __shfl(m, 2 * h);
            if (o > my || (o == my && h > t)) ++cnt;  // stable-argsort tie-break
        }
        if (t < H) smask[t] = (cnt < RH) ? 0.0f : 1.0f;
    }
    __syncthreads();

    // ---- Phase 3: apply. h = q/2 is CONSTANT per thread. ----
    const float m = smask[q >> 1];
    f32x4* o = out4 + xoff;
    #pragma unroll
    for (int j = 0; j < CPC / 4; ++j) {
        const f32x4 v = p[(size_t)j * 4 * HW4];  // L3-warm re-read
        __builtin_nontemporal_store(v * m, o + (size_t)j * 4 * HW4);
    }
}

// ---------------------------------------------------------------------------
extern "C" void kernel_launch(void* const* d_in, const int* in_sizes, int n_in,
                              void* d_out, int out_size, void* d_ws, size_t ws_size,
                              hipStream_t stream) {
    const f32x4* x4 = (const f32x4*)d_in[0];
    f32x4* out4 = (f32x4*)d_out;
    f32x4* partial4 = (f32x4*)d_ws;  // B*CHUNKS*HW floats (768 KB)
    unsigned int* counters =
        (unsigned int*)((float*)d_ws + (size_t)B * CHUNKS * HW);  // 64 uints

    k_init<<<1, 64, 0, stream>>>(counters);
    k_one<<<GRID, TPB, 0, stream>>>(x4, partial4, counters, out4);
}